// Round 1
// baseline (572.380 us; speedup 1.0000x reference)
//
#include <hip/hip_runtime.h>
#include <math.h>

// BeliveMapsNMS: 7x7 same-padded max-pool NMS on [32,4,512,512] f32.
// Outputs (concat flat): mask(0/1 f32), scores_abs, scores_rel.
// HBM-bound: 134 MB read x2 passes + 403 MB write.

#define H 512
#define W 512
#define PLANE_ELEMS (H * W)          // 262144
#define TX 64
#define TY 64
#define HALO 3
#define SIN_STRIDE 72                // (TX+6)=70 content + 1 offset + pad; 288 B (16B mult)
#define SROW_STRIDE 68               // TX + 4 pad; 272 B (16B mult)
#define OFF 1                        // storage offset so center lands 16B-aligned

// ---------------- Pass 1: per-plane max ----------------
__global__ __launch_bounds__(256) void vmax_kernel(const float* __restrict__ in,
                                                   unsigned int* __restrict__ vmax_bits) {
    // grid: (4 quarters, planes)
    const int q = blockIdx.x;
    const int plane = blockIdx.y;
    const float4* p = (const float4*)(in + (size_t)plane * PLANE_ELEMS + q * (PLANE_ELEMS / 4));
    float m = 0.0f;  // inputs are in [0,1): non-negative
    const int nvec = PLANE_ELEMS / 4 / 4;  // 16384 float4 per quarter
    for (int i = threadIdx.x; i < nvec; i += 256) {
        float4 v = p[i];
        m = fmaxf(m, fmaxf(fmaxf(v.x, v.y), fmaxf(v.z, v.w)));
    }
    // wave (64-lane) reduce
    #pragma unroll
    for (int o = 32; o > 0; o >>= 1) m = fmaxf(m, __shfl_down(m, o, 64));
    __shared__ float s[4];
    const int wid = threadIdx.x >> 6;
    const int lane = threadIdx.x & 63;
    if (lane == 0) s[wid] = m;
    __syncthreads();
    if (threadIdx.x == 0) {
        m = fmaxf(fmaxf(s[0], s[1]), fmaxf(s[2], s[3]));
        // non-negative IEEE floats: uint ordering == float ordering
        atomicMax(&vmax_bits[plane], __float_as_uint(m));
    }
}

// ---------------- Pass 2: NMS + thresholds + 3 outputs ----------------
__global__ __launch_bounds__(256) void nms_kernel(const float* __restrict__ in,
                                                  const unsigned int* __restrict__ vmax_bits,
                                                  float* __restrict__ out, int N) {
    // grid: (64 tiles/plane, planes). Tile layout: 8 x 8 tiles of 64x64.
    const int plane = blockIdx.y;
    const int tile = blockIdx.x;
    const int tx0 = (tile & 7) * TX;
    const int ty0 = (tile >> 3) * TY;
    const float* pin = in + (size_t)plane * PLANE_ELEMS;

    __shared__ __align__(16) float sIn[(TY + 6) * SIN_STRIDE];   // 20160 B
    __shared__ __align__(16) float sRow[(TY + 6) * SROW_STRIDE]; // 19040 B

    // Phase A: cooperative load (TY+6) x (TX+6) tile, -inf padding (matches
    // reduce_window's -inf identity so boundary max is bit-exact).
    for (int i = threadIdx.x; i < (TY + 6) * (TX + 6); i += 256) {
        const int y = i / (TX + 6);
        const int x = i - y * (TX + 6);
        const int gy = ty0 + y - HALO;
        const int gx = tx0 + x - HALO;
        float v = -INFINITY;
        if (gy >= 0 && gy < H && gx >= 0 && gx < W) v = pin[gy * W + gx];
        sIn[y * SIN_STRIDE + OFF + x] = v;
    }
    __syncthreads();

    // Phase B: horizontal 7-max. rowmax[y][x] = max(sIn[y][x .. x+6]), y in [0,TY+6)
    for (int i = threadIdx.x; i < (TY + 6) * TX; i += 256) {
        const int y = i >> 6;        // /TX
        const int x = i & (TX - 1);  // %TX
        const float* r = &sIn[y * SIN_STRIDE + OFF + x];
        float m = r[0];
        m = fmaxf(m, r[1]); m = fmaxf(m, r[2]); m = fmaxf(m, r[3]);
        m = fmaxf(m, r[4]); m = fmaxf(m, r[5]); m = fmaxf(m, r[6]);
        sRow[y * SROW_STRIDE + x] = m;
    }
    __syncthreads();

    const float vmax = __uint_as_float(vmax_bits[plane]);
    const float rel_thr = 0.05f * vmax;
    const float inv_vmax = 1.0f / vmax;  // |err| ~1 ulp << 2e-2 threshold

    float* __restrict__ omask = out;
    float* __restrict__ oabs = out + (size_t)N;
    float* __restrict__ orel = out + 2 * (size_t)N;
    const size_t outBase = (size_t)plane * PLANE_ELEMS;

    // Phase C: vertical 7-max + thresholds, float4 per work item.
    // 64 rows x 16 float4-groups = 1024 items, 4 per thread.
    for (int i = threadIdx.x; i < TY * (TX / 4); i += 256) {
        const int y = i >> 4;        // /(TX/4)
        const int xg = i & 15;
        const int x = xg * 4;
        const float* c = &sRow[y * SROW_STRIDE + x];
        float4 m = *(const float4*)c;
        #pragma unroll
        for (int dy = 1; dy < 7; ++dy) {
            float4 v = *(const float4*)(c + dy * SROW_STRIDE);
            m.x = fmaxf(m.x, v.x); m.y = fmaxf(m.y, v.y);
            m.z = fmaxf(m.z, v.z); m.w = fmaxf(m.w, v.w);
        }
        // center: sIn[(y+3)][OFF + 3 + x] -> word offset x+4, 16B aligned
        const float4 ctr = *(const float4*)&sIn[(y + HALO) * SIN_STRIDE + OFF + HALO + x];

        float4 msk, ab, rl;
        {
            const bool p0 = (m.x == ctr.x) & (ctr.x > 0.2f) & (ctr.x > rel_thr);
            const bool p1 = (m.y == ctr.y) & (ctr.y > 0.2f) & (ctr.y > rel_thr);
            const bool p2 = (m.z == ctr.z) & (ctr.z > 0.2f) & (ctr.z > rel_thr);
            const bool p3 = (m.w == ctr.w) & (ctr.w > 0.2f) & (ctr.w > rel_thr);
            msk.x = p0 ? 1.0f : 0.0f; ab.x = p0 ? ctr.x : 0.0f; rl.x = ab.x * inv_vmax;
            msk.y = p1 ? 1.0f : 0.0f; ab.y = p1 ? ctr.y : 0.0f; rl.y = ab.y * inv_vmax;
            msk.z = p2 ? 1.0f : 0.0f; ab.z = p2 ? ctr.z : 0.0f; rl.z = ab.z * inv_vmax;
            msk.w = p3 ? 1.0f : 0.0f; ab.w = p3 ? ctr.w : 0.0f; rl.w = ab.w * inv_vmax;
        }
        const size_t o = outBase + (size_t)(ty0 + y) * W + (tx0 + x);
        *(float4*)(omask + o) = msk;
        *(float4*)(oabs + o) = ab;
        *(float4*)(orel + o) = rl;
    }
}

extern "C" void kernel_launch(void* const* d_in, const int* in_sizes, int n_in,
                              void* d_out, int out_size, void* d_ws, size_t ws_size,
                              hipStream_t stream) {
    const float* in = (const float*)d_in[0];
    float* out = (float*)d_out;
    const int N = in_sizes[0];               // 33554432
    const int planes = N / PLANE_ELEMS;      // 128

    unsigned int* vmax_bits = (unsigned int*)d_ws;
    hipMemsetAsync(vmax_bits, 0, planes * sizeof(unsigned int), stream);

    vmax_kernel<<<dim3(4, planes), 256, 0, stream>>>(in, vmax_bits);
    nms_kernel<<<dim3((H / TX) * (W / TY), planes), 256, 0, stream>>>(in, vmax_bits, out, N);
}

// Round 3
// 492.877 us; speedup vs baseline: 1.1613x; 1.1613x over previous
//
#include <hip/hip_runtime.h>
#include <math.h>

// BeliveMapsNMS: 7x7 same-padded max-pool NMS on [32,4,512,512] f32.
// Outputs (concat flat): mask(0/1 f32), scores_abs, scores_rel.
// Write-bound: 403 MB out + 134 MB in. Structure: full-row tiles (512 x 16),
// horizontal 7-max in registers via wave shuffles (van Herk), rowmax in LDS,
// vertical 7-max van Herk from LDS, nontemporal stores.

#define H 512
#define W 512
#define PLANE_ELEMS (H * W)   // 262144
#define TH 16                 // output rows per block
#define LROWS (TH + 6)        // 22 loaded rows
#define NEG_INF (-INFINITY)

typedef float v4f __attribute__((ext_vector_type(4)));  // native vec for nontemporal

__device__ __forceinline__ float4 vmax4(float4 a, float4 b) {
    return make_float4(fmaxf(a.x, b.x), fmaxf(a.y, b.y), fmaxf(a.z, b.z), fmaxf(a.w, b.w));
}

__device__ __forceinline__ void nt_store4(float* p, float a, float b, float c, float d) {
    v4f v = {a, b, c, d};
    __builtin_nontemporal_store(v, (v4f*)p);
}

// ---------------- Pass 1: per-plane max ----------------
__global__ __launch_bounds__(256) void vmax_kernel(const float* __restrict__ in,
                                                   unsigned int* __restrict__ vmax_bits) {
    const int q = blockIdx.x;      // 4 quarters
    const int plane = blockIdx.y;  // 128 planes
    const float4* p = (const float4*)(in + (size_t)plane * PLANE_ELEMS + q * (PLANE_ELEMS / 4));
    float m = 0.0f;  // inputs in [0,1): non-negative
    const int nvec = PLANE_ELEMS / 4 / 4;  // 16384 float4 per quarter
    for (int i = threadIdx.x; i < nvec; i += 256) {
        float4 v = p[i];
        m = fmaxf(m, fmaxf(fmaxf(v.x, v.y), fmaxf(v.z, v.w)));
    }
    #pragma unroll
    for (int o = 32; o > 0; o >>= 1) m = fmaxf(m, __shfl_down(m, o, 64));
    __shared__ float s[4];
    if ((threadIdx.x & 63) == 0) s[threadIdx.x >> 6] = m;
    __syncthreads();
    if (threadIdx.x == 0) {
        m = fmaxf(fmaxf(s[0], s[1]), fmaxf(s[2], s[3]));
        atomicMax(&vmax_bits[plane], __float_as_uint(m));  // non-neg: uint order == float order
    }
}

// ---------------- Pass 2: NMS ----------------
__global__ __launch_bounds__(256) void nms_kernel(const float* __restrict__ in,
                                                  const unsigned int* __restrict__ vmax_bits,
                                                  float* __restrict__ out, int N) {
    const int plane = blockIdx.y;
    const int ty0 = blockIdx.x * TH;
    const float* pin = in + (size_t)plane * PLANE_ELEMS;

    __shared__ __align__(16) float sRow[LROWS * W];  // 45056 B -> 3 blocks/CU

    const int wid = threadIdx.x >> 6;   // wave 0..3
    const int lane = threadIdx.x & 63;
    const int c8 = lane << 3;           // 8 columns per lane; one wave = one full row

    // Phase A: load row, horizontal 7-max entirely in registers (shuffle halo).
    for (int r = wid; r < LROWS; r += 4) {
        const int gy = ty0 + r - 3;
        float4 v0, v1;
        if (gy >= 0 && gy < H) {
            const float4* row = (const float4*)(pin + (size_t)gy * W);
            v0 = row[lane * 2];
            v1 = row[lane * 2 + 1];
        } else {
            v0 = v1 = make_float4(NEG_INF, NEG_INF, NEG_INF, NEG_INF);
        }
        // left neighbor's last 3 cols (its v1.y/z/w), right neighbor's first 3 (v0.x/y/z)
        float l0 = __shfl_up(v1.y, 1, 64), l1 = __shfl_up(v1.z, 1, 64), l2 = __shfl_up(v1.w, 1, 64);
        float r0 = __shfl_down(v0.x, 1, 64), r1 = __shfl_down(v0.y, 1, 64), r2 = __shfl_down(v0.z, 1, 64);
        if (lane == 0) { l0 = NEG_INF; l1 = NEG_INF; l2 = NEG_INF; }
        if (lane == 63) { r0 = NEG_INF; r1 = NEG_INF; r2 = NEG_INF; }
        float a[14] = {l0, l1, l2, v0.x, v0.y, v0.z, v0.w, v1.x, v1.y, v1.z, v1.w, r0, r1, r2};
        // van Herk: rm[j] = max(a[j..j+6]), j=0..7; split at a[7]
        float A[7];
        A[6] = a[6];
        #pragma unroll
        for (int j = 5; j >= 0; --j) A[j] = fmaxf(a[j], A[j + 1]);
        float rm[8];
        rm[0] = A[0];
        float B = a[7];
        rm[1] = fmaxf(A[1], B);
        #pragma unroll
        for (int j = 2; j <= 6; ++j) { B = fmaxf(B, a[6 + j]); rm[j] = fmaxf(A[j], B); }
        B = fmaxf(B, a[13]);
        rm[7] = B;
        float4* dst = (float4*)&sRow[r * W + c8];
        dst[0] = make_float4(rm[0], rm[1], rm[2], rm[3]);
        dst[1] = make_float4(rm[4], rm[5], rm[6], rm[7]);
    }
    __syncthreads();

    const float vmax = __uint_as_float(vmax_bits[plane]);
    const float rel_thr = 0.05f * vmax;
    const float inv_vmax = 1.0f / vmax;

    float* __restrict__ omask = out;
    float* __restrict__ oabs = out + (size_t)N;
    float* __restrict__ orel = out + 2 * (size_t)N;

    // Phase B: vertical 7-max (van Herk over 14 rows -> 8 outputs per thread).
    const int strip = threadIdx.x >> 7;       // 0/1 -> rows 0..7 / 8..15
    const int cg = threadIdx.x & 127;
    const int c = cg << 2;
    const int y0 = strip << 3;

    float4 Lr[7], Aq[7];
    #pragma unroll
    for (int k = 0; k < 7; ++k) Lr[k] = *(const float4*)&sRow[(y0 + k) * W + c];
    Aq[6] = Lr[6];
    #pragma unroll
    for (int j = 5; j >= 0; --j) Aq[j] = vmax4(Lr[j], Aq[j + 1]);

    const int gy_base = ty0 + y0;
    float4 Bq;
    #pragma unroll
    for (int i = 0; i < 8; ++i) {
        float4 m;
        if (i == 0) {
            m = Aq[0];
        } else {
            float4 row = *(const float4*)&sRow[(y0 + 6 + i) * W + c];
            Bq = (i == 1) ? row : vmax4(Bq, row);
            m = (i == 7) ? Bq : vmax4(Aq[i], Bq);
        }
        const int gy = gy_base + i;
        const float4 ctr = *(const float4*)(pin + (size_t)gy * W + c);  // L2-hot
        const bool p0 = (m.x == ctr.x) & (ctr.x > 0.2f) & (ctr.x > rel_thr);
        const bool p1 = (m.y == ctr.y) & (ctr.y > 0.2f) & (ctr.y > rel_thr);
        const bool p2 = (m.z == ctr.z) & (ctr.z > 0.2f) & (ctr.z > rel_thr);
        const bool p3 = (m.w == ctr.w) & (ctr.w > 0.2f) & (ctr.w > rel_thr);
        const float a0 = p0 ? ctr.x : 0.0f, a1 = p1 ? ctr.y : 0.0f;
        const float a2 = p2 ? ctr.z : 0.0f, a3 = p3 ? ctr.w : 0.0f;
        const size_t o = (size_t)plane * PLANE_ELEMS + (size_t)gy * W + c;
        nt_store4(omask + o, p0 ? 1.0f : 0.0f, p1 ? 1.0f : 0.0f,
                             p2 ? 1.0f : 0.0f, p3 ? 1.0f : 0.0f);
        nt_store4(oabs + o, a0, a1, a2, a3);
        nt_store4(orel + o, a0 * inv_vmax, a1 * inv_vmax, a2 * inv_vmax, a3 * inv_vmax);
    }
}

extern "C" void kernel_launch(void* const* d_in, const int* in_sizes, int n_in,
                              void* d_out, int out_size, void* d_ws, size_t ws_size,
                              hipStream_t stream) {
    const float* in = (const float*)d_in[0];
    float* out = (float*)d_out;
    const int N = in_sizes[0];           // 33554432
    const int planes = N / PLANE_ELEMS;  // 128

    unsigned int* vmax_bits = (unsigned int*)d_ws;
    (void)hipMemsetAsync(vmax_bits, 0, planes * sizeof(unsigned int), stream);

    vmax_kernel<<<dim3(4, planes), 256, 0, stream>>>(in, vmax_bits);
    nms_kernel<<<dim3(H / TH, planes), 256, 0, stream>>>(in, vmax_bits, out, N);
}